// Round 4
// baseline (797.581 us; speedup 1.0000x reference)
//
#include <hip/hip_runtime.h>
#include <hip/hip_bf16.h>
#include <math.h>
#include <stdint.h>

using bf16 = __hip_bfloat16;
typedef __attribute__((ext_vector_type(4))) float f32x4;
typedef __attribute__((ext_vector_type(8))) short s16x8;

#define MFMA16(a, b, c) __builtin_amdgcn_mfma_f32_16x16x32_bf16(a, b, c, 0, 0, 0)

__device__ __forceinline__ void gload_lds16(const void* g, void* l) {
    __builtin_amdgcn_global_load_lds(
        (const __attribute__((address_space(1))) void*)g,
        (__attribute__((address_space(3))) void*)l, 16, 0, 0);
}

// ---------------- fp32 -> bf16 straight convert (8 elems/thread) ----------------
struct alignas(16) bf16x8s { bf16 v[8]; };

__global__ void cvt_f32_bf16(const float* __restrict__ in, bf16* __restrict__ out, long n) {
    long i = ((long)blockIdx.x * 256 + threadIdx.x) * 8;
    if (i >= n) return;
    float4 a = *(const float4*)(in + i);
    float4 b = *(const float4*)(in + i + 4);
    bf16x8s r;
    r.v[0] = __float2bfloat16(a.x); r.v[1] = __float2bfloat16(a.y);
    r.v[2] = __float2bfloat16(a.z); r.v[3] = __float2bfloat16(a.w);
    r.v[4] = __float2bfloat16(b.x); r.v[5] = __float2bfloat16(b.y);
    r.v[6] = __float2bfloat16(b.z); r.v[7] = __float2bfloat16(b.w);
    *(bf16x8s*)(out + i) = r;
}

// ---------------- fp32 [K][N] -> bf16 [N][K] transpose-convert ----------------
__global__ void transpose_cvt(const float* __restrict__ W, bf16* __restrict__ Wt, int K, int N) {
    __shared__ bf16 t[32][33];
    int tx = threadIdx.x & 31, ty = threadIdx.x >> 5;
    int n0 = blockIdx.x * 32, k0 = blockIdx.y * 32;
    #pragma unroll
    for (int r = ty; r < 32; r += 8)
        t[r][tx] = __float2bfloat16(W[(size_t)(k0 + r) * N + n0 + tx]);
    __syncthreads();
    #pragma unroll
    for (int r = ty; r < 32; r += 8)
        Wt[(size_t)(n0 + r) * K + k0 + tx] = t[tx][r];
}

// ---------------- 256x256 ring-2 GEMM, register-double-buffered phases ----------
// C[M,N] = A[M,K] * Bt[N,K]^T, bf16 in, fp32 acc.
// 512 thr = 8 waves (2M x 4N), per-wave 128x64, BK=64, 4 quadrant-phases/K-tile:
//   P0:(A0,B0) P1:(A1,B0) P2:(A0,B1) P3:(A1,B1)
// Fragments are ds_read ONE PHASE BEFORE use (reg double-buffer), so LDS reads
// overlap the previous phase's MFMA block. Each region read exactly once/tile
// (A0,B0 persist across their 2 uses): 24 ds_read_b128/wave/tile = minimum.
// LDS = 2 slots x 64KB (A0@0,A1@16K,B0@32K,B1@48K per slot). 16B-block XOR
// swizzle (block ^= row&7) via pre-swizzled GLOBAL source + linear LDS dest.
// 2 barriers/tile: MB (P0->P1, publishes B1(t), vmcnt(6)) and BB (P2->P3,
// publishes A0B0A1(t+1), vmcnt(2)). Stage issues: A0B0A1(t+1) in P0(t) (2-phase
// flight), B1(t+1) in P1(t) (3-phase flight). Drain only in the peeled tail.
// EPI 0: bf16 store. EPI 1: bias+gelu -> bf16. EPI 3: fp32 split-K partial.
// REQUIRES: M%256==0, N%256==0, (K/SPLITK)%64==0, K/SPLITK>=128,
//           gridDim.x*gridDim.y % 8 == 0.
template <int EPI, int SPLITK>
__global__ __launch_bounds__(512) void gemm_pipe(
    const bf16* __restrict__ A, const bf16* __restrict__ Bt,
    void* __restrict__ C, const float* __restrict__ bias,
    const float* __restrict__ resid, int M, int N, int K)
{
    __shared__ __align__(16) char smem[131072];
    const int tid = threadIdx.x;
    const int wid = tid >> 6, lane = tid & 63;
    const int quad = lane >> 4, l16 = lane & 15;
    const int wm = wid >> 2, wn = wid & 3;

    // XCD-aware bijective block swizzle (nwg % 8 == 0 guaranteed by launcher)
    const int nx = gridDim.x;
    const int nwg = nx * gridDim.y;
    int lin = blockIdx.y * nx + blockIdx.x;
    const int cpx = nwg >> 3;
    lin = (lin & 7) * cpx + (lin >> 3);
    const int bm = (lin % nx) * 256, bn = (lin / nx) * 256;

    const int KH = K / SPLITK;
    const int kbeg = blockIdx.z * KH;
    const int NT = KH / 64;

    // ---- staging (pre-swizzled global source, uniform region offsets) ----
    // thread owns 16B: LDS region-local row r0 = tid>>3 (+128 for 2nd chunk),
    // 16B-block pb = tid&7; global col block = pb ^ (r0&7) (chunk-invariant).
    const int r0 = tid >> 3, pb = tid & 7;
    const int gcol = ((pb ^ (r0 & 7)) << 3);
    const bf16* pA00 = A + (size_t)(bm + r0) * K + kbeg + gcol;
    const bf16* pB00 = Bt + (size_t)(bn + (r0 >> 5) * 64 + (r0 & 31)) * K + kbeg + gcol;
    const int dA = tid * 16;           // byte offset within A region
    const int dB = 32768 + tid * 16;   // byte offset of B0 region base

#define ST_A(h, sb, T1) { \
    gload_lds16(pA00 + (size_t)((h) * 64      ) * K + (T1) * 64, smem + (sb) + (h) * 16384 + dA); \
    gload_lds16(pA00 + (size_t)((h) * 64 + 128) * K + (T1) * 64, smem + (sb) + (h) * 16384 + dA + 8192); }
#define ST_B(h, sb, T1) { \
    gload_lds16(pB00 + (size_t)((h) * 32      ) * K + (T1) * 64, smem + (sb) + (h) * 16384 + dB); \
    gload_lds16(pB00 + (size_t)((h) * 32 + 128) * K + (T1) * 64, smem + (sb) + (h) * 16384 + dB + 8192); }

    // ---- fragment read offsets (bf16 elems; add slot elem offset) ----
    const int asw = l16 & 7;
    const int kx0 = (quad ^ asw) << 3;
    const int kx1 = ((4 + quad) ^ asw) << 3;
    const int aq0 = wm * 4096 + l16 * 64;           // A0 region
    const int aq1 = 8192 + wm * 4096 + l16 * 64;    // A1 region
    const int bq0 = 16384 + wn * 2048 + l16 * 64;   // B0 region
    const int bq1 = bq0 + 8192;                     // B1 region
    const bf16* sm = (const bf16*)smem;

#define LD_A(dst, off) { _Pragma("unroll") for (int mt = 0; mt < 4; ++mt) { \
    dst[0][mt] = *(const s16x8*)(sm + (off) + mt * 1024 + kx0); \
    dst[1][mt] = *(const s16x8*)(sm + (off) + mt * 1024 + kx1); } }
#define LD_B(dst, off) { _Pragma("unroll") for (int nt = 0; nt < 2; ++nt) { \
    dst[0][nt] = *(const s16x8*)(sm + (off) + nt * 1024 + kx0); \
    dst[1][nt] = *(const s16x8*)(sm + (off) + nt * 1024 + kx1); } }
#define MM(fa, fb, mo, no) { \
    __builtin_amdgcn_s_setprio(1); \
    _Pragma("unroll") for (int kh = 0; kh < 2; ++kh) \
    _Pragma("unroll") for (int mt = 0; mt < 4; ++mt) \
    _Pragma("unroll") for (int nt = 0; nt < 2; ++nt) \
        acc[(mo) + mt][(no) + nt] = MFMA16(fa[kh][mt], fb[kh][nt], acc[(mo) + mt][(no) + nt]); \
    __builtin_amdgcn_s_setprio(0); }

    f32x4 acc[8][4] = {};
    s16x8 fA0[2][4], fA1[2][4], fB0[2][2], fB1[2][2];

    // prologue: stage tile 0 (A0,B0,A1 first -> 6 loads, then B1 -> 2 loads)
    ST_A(0, 0, 0); ST_B(0, 0, 0); ST_A(1, 0, 0);
    ST_B(1, 0, 0);
    asm volatile("s_waitcnt vmcnt(2)\ns_barrier" ::: "memory");  // pub A0B0A1(0)
    LD_A(fA0, aq0); LD_B(fB0, bq0);

    for (int t = 0; t < NT - 1; ++t) {
        const int ce = (t & 1) << 15;       // current slot, bf16-elem offset
        const int ne = ce ^ 32768;          // next slot
        const int nb = ne << 1;             // next slot, byte offset
        // P0: MFMA(A0,B0); read A1(t); stage A0,B0,A1(t+1)
        LD_A(fA1, ce + aq1);
        ST_A(0, nb, t + 1); ST_B(0, nb, t + 1); ST_A(1, nb, t + 1);
        MM(fA0, fB0, 0, 0);
        asm volatile("s_waitcnt vmcnt(6)\ns_barrier" ::: "memory");  // MB: pub B1(t)
        // P1: MFMA(A1,B0); read B1(t); stage B1(t+1)
        LD_B(fB1, ce + bq1);
        ST_B(1, nb, t + 1);
        MM(fA1, fB0, 4, 0);
        // P2: MFMA(A0,B1)
        MM(fA0, fB1, 0, 2);
        asm volatile("s_waitcnt vmcnt(2)\ns_barrier" ::: "memory");  // BB: pub A0B0A1(t+1)
        // P3: MFMA(A1,B1); read A0,B0(t+1) from next slot
        LD_A(fA0, ne + aq0); LD_B(fB0, ne + bq0);
        MM(fA1, fB1, 4, 2);
    }
    {   // peeled last tile (no staging; outstanding = B1(NT-1) only)
        const int ce = ((NT - 1) & 1) << 15;
        LD_A(fA1, ce + aq1);
        MM(fA0, fB0, 0, 0);
        asm volatile("s_waitcnt vmcnt(0)\ns_barrier" ::: "memory");  // pub B1(NT-1)
        LD_B(fB1, ce + bq1);
        MM(fA1, fB0, 4, 0);
        MM(fA0, fB1, 0, 2);
        MM(fA1, fB1, 4, 2);
    }
#undef ST_A
#undef ST_B
#undef LD_A
#undef LD_B
#undef MM

    float* Cp = (float*)C;
    if (EPI == 3) Cp += (size_t)blockIdx.z * M * N;

    #pragma unroll
    for (int m = 0; m < 8; ++m) {
        #pragma unroll
        for (int n = 0; n < 4; ++n) {
            #pragma unroll
            for (int r = 0; r < 4; ++r) {
                int row = bm + wm * 128 + m * 16 + quad * 4 + r;
                int col = bn + wn * 64 + n * 16 + l16;
                float v = acc[m][n][r];
                if (EPI == 0) {
                    ((bf16*)C)[(size_t)row * N + col] = __float2bfloat16(v);
                } else if (EPI == 1) {
                    float xx = v + bias[col];
                    float g = 0.5f * xx * (1.0f + erff(xx * 0.7071067811865475f));
                    ((bf16*)C)[(size_t)row * N + col] = __float2bfloat16(g);
                } else if (EPI == 2) {
                    ((float*)C)[(size_t)row * N + col] =
                        v + bias[col] + resid[(size_t)row * N + col];
                } else {
                    Cp[(size_t)row * N + col] = v;
                }
            }
        }
    }
}

// ---------------- RoPE (reference indexes sin/cos by BATCH, not position) --------
__global__ void rope_kernel(const bf16* __restrict__ in, bf16* __restrict__ out,
                            const float* __restrict__ sn, const float* __restrict__ cs,
                            int S, int D, int instride) {
    int row = blockIdx.x;
    int pos = row / S;                 // batch index — matches reference broadcast
    const int half = D >> 1;
    const bf16* r = in + (size_t)row * instride;
    bf16* o = out + (size_t)row * D;
    for (int j = threadIdx.x; j < half; j += 256) {
        uint32_t pr = *(const uint32_t*)(r + 2 * j);
        float x1 = __uint_as_float(pr << 16);
        float x2 = __uint_as_float(pr & 0xffff0000u);
        float c = cs[(size_t)pos * half + j], s = sn[(size_t)pos * half + j];
        o[j]        = __float2bfloat16(x1 * c - x2 * s);
        o[half + j] = __float2bfloat16(x1 * s + x2 * c);
    }
}

// ---------------- V transpose per head: v[b,s,h,d] (strided) -> vt[bh, d, s] -----
__global__ void vtrans_kernel(const bf16* __restrict__ v, bf16* __restrict__ vt,
                              int S, int D, int H, int instride) {
    __shared__ bf16 t[32][33];
    int bh = blockIdx.z, b = bh >> 4, h = bh & 15;
    int s0 = blockIdx.x * 32, d0 = blockIdx.y * 32;
    int tx = threadIdx.x & 31, ty = threadIdx.x >> 5;
    #pragma unroll
    for (int r = ty; r < 32; r += 8)
        t[r][tx] = v[(size_t)(b * S + s0 + r) * instride + h * 128 + d0 + tx];
    __syncthreads();
    #pragma unroll
    for (int r = ty; r < 32; r += 8)
        vt[((size_t)bh * 128 + d0 + r) * S + s0 + tx] = t[tx][r];
}

// ---------------- Flash attention, transposed-score form ----------------
__global__ __launch_bounds__(256, 4) void attn_kernel(
    const bf16* __restrict__ q, const bf16* __restrict__ k, const bf16* __restrict__ vt,
    float* __restrict__ o, int S, int D, int H)
{
    __shared__ __align__(16) char smem[40960];
    bf16* Ks = (bf16*)smem;                 // [64 k][128 d], 16B-block XOR swizzle
    bf16* Vs = (bf16*)(smem + 16384);       // [128 d][64 k], swizzled
    bf16* Ps = (bf16*)(smem + 32768);       // per-wave [16 q][64 k], swizzled

    const int tid = threadIdx.x, wid = tid >> 6, lane = tid & 63;
    const int quad = lane >> 4, l16 = lane & 15;
    const int bh = blockIdx.x, b = bh >> 4, h = bh & 15;
    const int qt = gridDim.y - 1 - blockIdx.y;     // big tiles dispatched first
    const float scale = 0.08838834764831845f;      // 1/sqrt(128)

    s16x8 qf[4];
    const bf16* qrow = q + ((size_t)(b * S + qt * 64 + wid * 16 + l16)) * D + h * 128;
    #pragma unroll
    for (int ks = 0; ks < 4; ++ks)
        qf[ks] = *(const s16x8*)(qrow + ks * 32 + quad * 8);

    f32x4 oacc[8] = {};
    float mstate = -INFINITY, lstate = 0.f;

    const bf16* kb0 = k + (size_t)(b * S) * D + h * 128;
    const bf16* vb0 = vt + (size_t)bh * 128 * S;
    bf16* psw = Ps + wid * 16 * 64;
    const int sw = l16 & 7;
    const int nch = qt + 1;

    for (int kc = 0; kc < nch; ++kc) {
        __syncthreads();
        #pragma unroll
        for (int c = 0; c < 4; ++c) {
            int choff = (wid * 4 + c) << 10;
            int off = choff + lane * 16;
            int rk = off >> 8, bk = (off & 255) >> 4;
            gload_lds16(kb0 + (size_t)(kc * 64 + rk) * D + ((bk ^ (rk & 7)) << 3),
                        (char*)Ks + choff);
            int rv = off >> 7, bv = (off & 127) >> 4;
            gload_lds16(vb0 + (size_t)rv * S + kc * 64 + ((bv ^ (rv & 7)) << 3),
                        (char*)Vs + choff);
        }
        __syncthreads();

        f32x4 sacc[4] = {};
        #pragma unroll
        for (int mt = 0; mt < 4; ++mt) {
            #pragma unroll
            for (int ks = 0; ks < 4; ++ks) {
                s16x8 kf = *(const s16x8*)(Ks + (mt * 16 + l16) * 128 +
                                           (((ks * 4 + quad) ^ sw) << 3));
                sacc[mt] = MFMA16(kf, qf[ks], sacc[mt]);
            }
        }

        const bool need_mask = (kc == qt);
        #pragma unroll
        for (int mt = 0; mt < 4; ++mt)
            #pragma unroll
            for (int r = 0; r < 4; ++r) {
                float vv = sacc[mt][r] * scale;
                if (need_mask) {
                    int kl = mt * 16 + quad * 4 + r;
                    if (kl > wid * 16 + l16) vv = -INFINITY;
                }
                sacc[mt][r] = vv;
            }

        float mx = fmaxf(fmaxf(fmaxf(sacc[0][0], sacc[0][1]), fmaxf(sacc[0][2], sacc[0][3])),
                         fmaxf(fmaxf(sacc[1][0], sacc[1][1]), fmaxf(sacc[1][2], sacc[1][3])));
        mx = fmaxf(mx, fmaxf(fmaxf(fmaxf(sacc[2][0], sacc[2][1]), fmaxf(sacc[2][2], sacc[2][3])),
                             fmaxf(fmaxf(sacc[3][0], sacc[3][1]), fmaxf(sacc[3][2], sacc[3][3]))));
        mx = fmaxf(mx, __shfl_xor(mx, 16, 64));
        mx = fmaxf(mx, __shfl_xor(mx, 32, 64));
        float mnew = fmaxf(mstate, mx);
        float alpha = __expf(mstate - mnew);
        float rs = 0.f;
        #pragma unroll
        for (int mt = 0; mt < 4; ++mt)
            #pragma unroll
            for (int r = 0; r < 4; ++r) {
                float p = __expf(sacc[mt][r] - mnew);
                sacc[mt][r] = p;
                rs += p;
            }
        rs += __shfl_xor(rs, 16, 64);
        rs += __shfl_xor(rs, 32, 64);
        lstate = lstate * alpha + rs;
        mstate = mnew;
        #pragma unroll
        for (int mt = 0; mt < 8; ++mt)
            #pragma unroll
            for (int r = 0; r < 4; ++r) oacc[mt][r] *= alpha;

        #pragma unroll
        for (int mt = 0; mt < 4; ++mt)
            #pragma unroll
            for (int r = 0; r < 4; ++r) {
                int kl = mt * 16 + quad * 4 + r;
                psw[l16 * 64 + (((kl >> 3) ^ sw) << 3) + (kl & 7)] =
                    __float2bfloat16(sacc[mt][r]);
            }

        #pragma unroll
        for (int ks2 = 0; ks2 < 2; ++ks2) {
            s16x8 pf = *(const s16x8*)(psw + l16 * 64 + (((ks2 * 4 + quad) ^ sw) << 3));
            #pragma unroll
            for (int mt = 0; mt < 8; ++mt) {
                s16x8 vf = *(const s16x8*)(Vs + (mt * 16 + l16) * 64 +
                                           (((ks2 * 4 + quad) ^ sw) << 3));
                oacc[mt] = MFMA16(vf, pf, oacc[mt]);
            }
        }
    }

    float inv = 1.0f / lstate;
    __syncthreads();
    float* osw = (float*)smem + wid * 16 * 130;
    #pragma unroll
    for (int mt = 0; mt < 8; ++mt)
        #pragma unroll
        for (int r = 0; r < 4; ++r)
            osw[l16 * 130 + mt * 16 + quad * 4 + r] = oacc[mt][r] * inv;
    float* obase = o + (size_t)(b * S + qt * 64 + wid * 16) * D + h * 128;
    #pragma unroll
    for (int r16 = 0; r16 < 16; ++r16) {
        float2 val = *(const float2*)(osw + r16 * 130 + lane * 2);
        *(float2*)(obase + (size_t)r16 * D + lane * 2) = val;
    }
}

// ---------------- LayerNorm over D=2048: x = a (+b) (+c) (+bias), dual out ------
__global__ __launch_bounds__(256) void ln_kernel(
    const float* __restrict__ a, const float* __restrict__ b,
    const float* __restrict__ c, const float* __restrict__ bias,
    float* __restrict__ outf, bf16* __restrict__ outb, int D)
{
    int row = blockIdx.x;
    const float* pa = a + (size_t)row * D;
    const float* pb = b ? b + (size_t)row * D : nullptr;
    const float* pc = c ? c + (size_t)row * D : nullptr;
    float v[8];
    float sum = 0.f, sq = 0.f;
    #pragma unroll
    for (int u = 0; u < 8; ++u) {
        int j = threadIdx.x + u * 256;
        float x = pa[j];
        if (pb) x += pb[j];
        if (pc) x += pc[j];
        if (bias) x += bias[j];
        v[u] = x; sum += x; sq += x * x;
    }
    #pragma unroll
    for (int off = 32; off > 0; off >>= 1) {
        sum += __shfl_down(sum, off, 64);
        sq  += __shfl_down(sq,  off, 64);
    }
    __shared__ float red[8];
    int wid = threadIdx.x >> 6, lane = threadIdx.x & 63;
    if (lane == 0) { red[wid] = sum; red[4 + wid] = sq; }
    __syncthreads();
    sum = red[0] + red[1] + red[2] + red[3];
    sq  = red[4] + red[5] + red[6] + red[7];
    float mean = sum / D;
    float var = sq / D - mean * mean;
    float rstd = rsqrtf(fmaxf(var, 0.f) + 1e-5f);
    float* pof = outf ? outf + (size_t)row * D : nullptr;
    bf16* pob = outb ? outb + (size_t)row * D : nullptr;
    #pragma unroll
    for (int u = 0; u < 8; ++u) {
        int j = threadIdx.x + u * 256;
        float y = (v[u] - mean) * rstd;
        if (pof) pof[j] = y;
        if (pob) pob[j] = __float2bfloat16(y);
    }
}

// ---------------- launch ----------------
// Workspace plan (proven budget: 232 MB).
//   [  0, 16) xb        -> qr (after QKV)   -> outb (after attn)
//   [ 16, 48) Wq^T/Wk^T -> kr@16-32         -> W1t (after LN1) -> W2t (after FFN1)
//   [ 32, 40) Wv^T      (dead after QKV)
//   [ 40, 88) qkv       -> attn fp32 @40-72 (after rope/vtrans)
//   [ 72,104) (qkv tail + vt@88-104) -> outf fp32 (after attn)
//   [104,168) h (FFN1 out, bf16 [M][8192])
//   [168,232) p0|p1 (FFN2 split-K fp32 partials)
extern "C" void kernel_launch(void* const* d_in, const int* in_sizes, int n_in,
                              void* d_out, int out_size, void* d_ws, size_t ws_size,
                              hipStream_t stream) {
    const float* x  = (const float*)d_in[0];
    const float* Wq = (const float*)d_in[1];
    const float* Wk = (const float*)d_in[2];
    const float* Wv = (const float*)d_in[3];
    const float* W1 = (const float*)d_in[4];
    const float* b1 = (const float*)d_in[5];
    const float* W2 = (const float*)d_in[6];
    const float* b2 = (const float*)d_in[7];
    const float* sn = (const float*)d_in[8];
    const float* cs = (const float*)d_in[9];

    const int B = 2, S = 2048, D = 2048, H = 16, Dff = 8192;
    const int M = B * S;                       // 4096
    const int NQKV = 3 * D;                    // 6144
    char* ws = (char*)d_ws;
    const size_t MB = 1024 * 1024;

    const size_t o_xb   = 0;                   // bf16 [M][D], 16 MB
    const size_t o_Wqkv = 16 * MB;             // bf16 [6144][2048], 24 MB
    const size_t o_qkv  = 40 * MB;             // bf16 [M][6144], 48 MB
    const size_t o_qr   = 0;                   // bf16 16 MB (xb dead)
    const size_t o_kr   = 16 * MB;             // bf16 16 MB (Wq^T/Wk^T dead)
    const size_t o_vt   = 88 * MB;             // bf16 [BH][128][S], 16 MB
    const size_t o_attn = 40 * MB;             // fp32 [M][D], 32 MB (qkv dead)
    const size_t o_outb = 0;                   // bf16 16 MB (qr dead)
    const size_t o_outf = 72 * MB;             // fp32 32 MB (qkv tail + vt dead)
    const size_t o_W1t  = 16 * MB;             // bf16 [8192][2048], 32 MB (kr/attn dead)
    const size_t o_h    = 104 * MB;            // bf16 [M][8192], 64 MB
    const size_t o_W2t  = 16 * MB;             // bf16 [2048][8192], 32 MB (W1t dead)
    const size_t o_p    = 168 * MB;            // fp32 2x[M][D], 64 MB

    // 1. x -> bf16; Wq/Wk/Wv -> stacked transposed bf16 [6144][2048]
    long nx = (long)M * D;
    cvt_f32_bf16<<<nx / 2048, 256, 0, stream>>>(x, (bf16*)(ws + o_xb), nx);
    transpose_cvt<<<dim3(D / 32, D / 32), 256, 0, stream>>>(
        Wq, (bf16*)(ws + o_Wqkv), D, D);
    transpose_cvt<<<dim3(D / 32, D / 32), 256, 0, stream>>>(
        Wk, (bf16*)(ws + o_Wqkv) + (size_t)D * D, D, D);
    transpose_cvt<<<dim3(D / 32, D / 32), 256, 0, stream>>>(
        Wv, (bf16*)(ws + o_Wqkv) + 2 * (size_t)D * D, D, D);

    // 2. fused QKV projection: [M][2048] x [6144][2048]^T -> [M][6144]
    gemm_pipe<0, 1><<<dim3(M / 256, NQKV / 256), 512, 0, stream>>>(
        (bf16*)(ws + o_xb), (bf16*)(ws + o_Wqkv), ws + o_qkv, nullptr, nullptr,
        M, NQKV, D);

    // 3. RoPE + V transpose (strided reads from fused buffer)
    rope_kernel<<<M, 256, 0, stream>>>((bf16*)(ws + o_qkv), (bf16*)(ws + o_qr),
                                       sn, cs, S, D, NQKV);
    rope_kernel<<<M, 256, 0, stream>>>((bf16*)(ws + o_qkv) + D, (bf16*)(ws + o_kr),
                                       sn, cs, S, D, NQKV);
    vtrans_kernel<<<dim3(S / 32, 4, B * H), 256, 0, stream>>>(
        (bf16*)(ws + o_qkv) + 2 * D, (bf16*)(ws + o_vt), S, D, H, NQKV);

    // 4. causal flash attention -> fp32 [M][D]
    attn_kernel<<<dim3(B * H, S / 64), 256, 0, stream>>>(
        (bf16*)(ws + o_qr), (bf16*)(ws + o_kr), (bf16*)(ws + o_vt),
        (float*)(ws + o_attn), S, D, H);

    // 5. LN(attn + x) -> outf (fp32, residual for LN2) + outb (bf16, FFN1 input)
    ln_kernel<<<M, 256, 0, stream>>>((float*)(ws + o_attn), x, nullptr, nullptr,
                                     (float*)(ws + o_outf), (bf16*)(ws + o_outb), D);

    // 6. W1^T (late: reuses kr/attn regions), then FFN1: gelu(out@W1+b1) -> bf16 h
    transpose_cvt<<<dim3(Dff / 32, D / 32), 256, 0, stream>>>(
        W1, (bf16*)(ws + o_W1t), D, Dff);
    gemm_pipe<1, 1><<<dim3(M / 256, Dff / 256), 512, 0, stream>>>(
        (bf16*)(ws + o_outb), (bf16*)(ws + o_W1t), ws + o_h, b1, nullptr, M, Dff, D);

    // 7. W2^T (late: reuses W1t region), then FFN2 split-K=2 -> p0|p1 fp32
    transpose_cvt<<<dim3(D / 32, Dff / 32), 256, 0, stream>>>(
        W2, (bf16*)(ws + o_W2t), Dff, D);
    gemm_pipe<3, 2><<<dim3(M / 256, D / 256, 2), 512, 0, stream>>>(
        (bf16*)(ws + o_h), (bf16*)(ws + o_W2t), ws + o_p, nullptr, nullptr, M, D, Dff);

    // 8. LN2( p0 + p1 + outf + b2 ) -> d_out fp32
    ln_kernel<<<M, 256, 0, stream>>>((float*)(ws + o_p),
                                     (float*)(ws + o_p) + (size_t)M * D,
                                     (float*)(ws + o_outf), b2,
                                     (float*)d_out, nullptr, D);
}

// Round 5
// 796.157 us; speedup vs baseline: 1.0018x; 1.0018x over previous
//
#include <hip/hip_runtime.h>
#include <hip/hip_bf16.h>
#include <math.h>
#include <stdint.h>

using bf16 = __hip_bfloat16;
typedef __attribute__((ext_vector_type(4))) float f32x4;
typedef __attribute__((ext_vector_type(8))) short s16x8;

#define MFMA16(a, b, c) __builtin_amdgcn_mfma_f32_16x16x32_bf16(a, b, c, 0, 0, 0)

__device__ __forceinline__ void gload_lds16(const void* g, void* l) {
    __builtin_amdgcn_global_load_lds(
        (const __attribute__((address_space(1))) void*)g,
        (__attribute__((address_space(3))) void*)l, 16, 0, 0);
}

// ---------------- fp32 -> bf16 straight convert (8 elems/thread) ----------------
struct alignas(16) bf16x8s { bf16 v[8]; };

__global__ void cvt_f32_bf16(const float* __restrict__ in, bf16* __restrict__ out, long n) {
    long i = ((long)blockIdx.x * 256 + threadIdx.x) * 8;
    if (i >= n) return;
    float4 a = *(const float4*)(in + i);
    float4 b = *(const float4*)(in + i + 4);
    bf16x8s r;
    r.v[0] = __float2bfloat16(a.x); r.v[1] = __float2bfloat16(a.y);
    r.v[2] = __float2bfloat16(a.z); r.v[3] = __float2bfloat16(a.w);
    r.v[4] = __float2bfloat16(b.x); r.v[5] = __float2bfloat16(b.y);
    r.v[6] = __float2bfloat16(b.z); r.v[7] = __float2bfloat16(b.w);
    *(bf16x8s*)(out + i) = r;
}

// ---------------- fp32 [K][N] -> bf16 [N][K] transpose-convert ----------------
__global__ void transpose_cvt(const float* __restrict__ W, bf16* __restrict__ Wt, int K, int N) {
    __shared__ bf16 t[32][33];
    int tx = threadIdx.x & 31, ty = threadIdx.x >> 5;
    int n0 = blockIdx.x * 32, k0 = blockIdx.y * 32;
    #pragma unroll
    for (int r = ty; r < 32; r += 8)
        t[r][tx] = __float2bfloat16(W[(size_t)(k0 + r) * N + n0 + tx]);
    __syncthreads();
    #pragma unroll
    for (int r = ty; r < 32; r += 8)
        Wt[(size_t)(n0 + r) * K + k0 + tx] = t[tx][r];
}

// ---------------- 256x256 GEMM, m201-style 8-phase lockstep schedule ------------
// C[M,N] = A[M,K] * Bt[N,K]^T, bf16 in, fp32 acc.
// 512 thr = 8 waves (2M x 4N), per-wave 128x64, BK=64.
// 8 phases per iteration = 2 K-tiles (even tile -> LDS slot0, odd -> slot1).
// Per phase: {ds_read subtile | stage 1 half-tile} -> barrier -> lgkmcnt(0) ->
//            setprio(1) 16 MFMA setprio(0) -> barrier.
// Quadrant ladder per tile: (0,0)->(0,1)->(1,1)->(1,0); A/B frags reg-carried so
// region last-reads ladder A0@p1, B1@p2, A1@p3, B0@p4 (B0 re-read at p4).
// Stage stream (1 half-tile/phase, canonical order A0,B1,A1,B0 per tile):
//   ph1: B0(T+1)->s1 | ph2: A0(T+2)->s0 | ph3: B1(T+2)->s0 | ph4: A1(T+2)->s0
//   ph5: B0(T+2)->s0 | ph6: A0(T+3)->s1 | ph7: B1(T+3)->s1 | ph8: A1(T+3)->s1
// Each stage targets a region whose last ds_read was the previous phase (WAR-safe
// across the intervening double barrier). vmcnt(6) ONLY at ph4/ph8: keeps the 3
// newest half-tiles (6 loads) in flight, publishes staged<=p-3 => tile T+1 fully
// published at ph4, T+2 at ph8. Prologue: 7 half-tiles then vmcnt(6). Peeled
// final iteration: stage only B0(NT-1) at ph1, vmcnt(0) at ph4.
// 16B-block XOR swizzle (block ^= row&7), pre-swizzled GLOBAL source + linear
// LDS dest, read with same XOR (zero bank conflicts, verified R2-R4).
// EPI 0: bf16 store. EPI 1: bias+gelu -> bf16. EPI 3: fp32 split-K partial.
// REQUIRES: M%256==0, N%256==0, (K/SPLITK)%128==0, gridDim.x*gridDim.y % 8 == 0.
template <int EPI, int SPLITK>
__global__ __launch_bounds__(512) void gemm_pipe(
    const bf16* __restrict__ A, const bf16* __restrict__ Bt,
    void* __restrict__ C, const float* __restrict__ bias,
    const float* __restrict__ resid, int M, int N, int K)
{
    __shared__ __align__(16) char smem[131072];
    const int tid = threadIdx.x;
    const int wid = tid >> 6, lane = tid & 63;
    const int quad = lane >> 4, l16 = lane & 15;
    const int wm = wid >> 2, wn = wid & 3;

    // XCD-aware bijective block swizzle (nwg % 8 == 0 guaranteed by launcher)
    const int nx = gridDim.x;
    const int nwg = nx * gridDim.y;
    int lin = blockIdx.y * nx + blockIdx.x;
    const int cpx = nwg >> 3;
    lin = (lin & 7) * cpx + (lin >> 3);
    const int bm = (lin % nx) * 256, bn = (lin / nx) * 256;

    const int KH = K / SPLITK;
    const int kbeg = blockIdx.z * KH;
    const int NT = KH / 64;

    // ---- staging (pre-swizzled global source; verified R2-R4) ----
    const int r0 = tid >> 3, pb = tid & 7;
    const int gcol = ((pb ^ (r0 & 7)) << 3);
    const bf16* pA00 = A + (size_t)(bm + r0) * K + kbeg + gcol;
    const bf16* pB00 = Bt + (size_t)(bn + (r0 >> 5) * 64 + (r0 & 31)) * K + kbeg + gcol;
    const int dA = tid * 16;           // byte offset within A-region pair
    const int dB = 32768 + tid * 16;   // byte offset of B0 region base

#define ST_A(h, sb, T1) { \
    gload_lds16(pA00 + (size_t)((h) * 64      ) * K + (T1) * 64, smem + (sb) + (h) * 16384 + dA); \
    gload_lds16(pA00 + (size_t)((h) * 64 + 128) * K + (T1) * 64, smem + (sb) + (h) * 16384 + dA + 8192); }
#define ST_B(h, sb, T1) { \
    gload_lds16(pB00 + (size_t)((h) * 32      ) * K + (T1) * 64, smem + (sb) + (h) * 16384 + dB); \
    gload_lds16(pB00 + (size_t)((h) * 32 + 128) * K + (T1) * 64, smem + (sb) + (h) * 16384 + dB + 8192); }

    // ---- fragment read offsets (bf16 elems; +32768 elems for slot1) ----
    const int asw = l16 & 7;
    const int kx0 = (quad ^ asw) << 3;
    const int kx1 = ((4 + quad) ^ asw) << 3;
    const int aq0 = wm * 4096 + l16 * 64;           // A0 region
    const int aq1 = 8192 + aq0;                     // A1 region
    const int bq0 = 16384 + wn * 2048 + l16 * 64;   // B0 region
    const int bq1 = bq0 + 8192;                     // B1 region
    const bf16* sm = (const bf16*)smem;

#define LD_A(dst, off) { _Pragma("unroll") for (int mt = 0; mt < 4; ++mt) { \
    dst[0][mt] = *(const s16x8*)(sm + (off) + mt * 1024 + kx0); \
    dst[1][mt] = *(const s16x8*)(sm + (off) + mt * 1024 + kx1); } }
#define LD_B(dst, off) { _Pragma("unroll") for (int nt = 0; nt < 2; ++nt) { \
    dst[0][nt] = *(const s16x8*)(sm + (off) + nt * 1024 + kx0); \
    dst[1][nt] = *(const s16x8*)(sm + (off) + nt * 1024 + kx1); } }
#define MM(fa, fb, mo, no) { \
    __builtin_amdgcn_s_setprio(1); \
    _Pragma("unroll") for (int kh = 0; kh < 2; ++kh) \
    _Pragma("unroll") for (int mt = 0; mt < 4; ++mt) \
    _Pragma("unroll") for (int nt = 0; nt < 2; ++nt) \
        acc[(mo) + mt][(no) + nt] = MFMA16(fa[kh][mt], fb[kh][nt], acc[(mo) + mt][(no) + nt]); \
    __builtin_amdgcn_s_setprio(0); }
#define BARM  asm volatile("s_barrier" ::: "memory")
#define LGKM0 asm volatile("s_waitcnt lgkmcnt(0)" ::: "memory")

    f32x4 acc[8][4] = {};
    s16x8 fA[2][4], fBa[2][2], fBb[2][2];

    // prologue: tile0 (A0,B1,A1,B0)->slot0; tile1 (A0,B1,A1)->slot1; publish tile0
    ST_A(0, 0, 0); ST_B(1, 0, 0); ST_A(1, 0, 0); ST_B(0, 0, 0);
    ST_A(0, 65536, 1); ST_B(1, 65536, 1); ST_A(1, 65536, 1);
    asm volatile("s_waitcnt vmcnt(6)" ::: "memory");
    BARM;

    for (int it = 0; it < NT / 2 - 1; ++it) {
        const int T = 2 * it;
        // ph1: tile T q(0,0); stage B0(T+1)->s1
        LD_A(fA, aq0); LD_B(fBa, bq0);
        ST_B(0, 65536, T + 1);
        BARM; LGKM0; MM(fA, fBa, 0, 0); BARM;
        // ph2: q(0,1); stage A0(T+2)->s0
        LD_B(fBb, bq1);
        ST_A(0, 0, T + 2);
        BARM; LGKM0; MM(fA, fBb, 0, 2); BARM;
        // ph3: q(1,1); stage B1(T+2)->s0
        LD_A(fA, aq1);
        ST_B(1, 0, T + 2);
        BARM; LGKM0; MM(fA, fBb, 4, 2); BARM;
        // ph4: q(1,0); stage A1(T+2)->s0; vmcnt(6) publishes tile T+1
        LD_B(fBa, bq0);
        ST_A(1, 0, T + 2);
        asm volatile("s_waitcnt vmcnt(6)" ::: "memory");
        BARM; LGKM0; MM(fA, fBa, 4, 0); BARM;
        // ph5: tile T+1 q(0,0) (slot1); stage B0(T+2)->s0
        LD_A(fA, 32768 + aq0); LD_B(fBa, 32768 + bq0);
        ST_B(0, 0, T + 2);
        BARM; LGKM0; MM(fA, fBa, 0, 0); BARM;
        // ph6: q(0,1); stage A0(T+3)->s1
        LD_B(fBb, 32768 + bq1);
        ST_A(0, 65536, T + 3);
        BARM; LGKM0; MM(fA, fBb, 0, 2); BARM;
        // ph7: q(1,1); stage B1(T+3)->s1
        LD_A(fA, 32768 + aq1);
        ST_B(1, 65536, T + 3);
        BARM; LGKM0; MM(fA, fBb, 4, 2); BARM;
        // ph8: q(1,0); stage A1(T+3)->s1; vmcnt(6) publishes tile T+2
        LD_B(fBa, 32768 + bq0);
        ST_A(1, 65536, T + 3);
        asm volatile("s_waitcnt vmcnt(6)" ::: "memory");
        BARM; LGKM0; MM(fA, fBa, 4, 0); BARM;
    }
    {   // peeled final iteration (tiles NT-2, NT-1)
        // ph1: stage last half-tile B0(NT-1)->s1
        LD_A(fA, aq0); LD_B(fBa, bq0);
        ST_B(0, 65536, NT - 1);
        BARM; LGKM0; MM(fA, fBa, 0, 0); BARM;
        // ph2
        LD_B(fBb, bq1);
        BARM; LGKM0; MM(fA, fBb, 0, 2); BARM;
        // ph3
        LD_A(fA, aq1);
        BARM; LGKM0; MM(fA, fBb, 4, 2); BARM;
        // ph4: drain all remaining staged loads (tile NT-1 complete)
        LD_B(fBa, bq0);
        asm volatile("s_waitcnt vmcnt(0)" ::: "memory");
        BARM; LGKM0; MM(fA, fBa, 4, 0); BARM;
        // ph5-8: tile NT-1 (slot1), no staging
        LD_A(fA, 32768 + aq0); LD_B(fBa, 32768 + bq0);
        BARM; LGKM0; MM(fA, fBa, 0, 0); BARM;
        LD_B(fBb, 32768 + bq1);
        BARM; LGKM0; MM(fA, fBb, 0, 2); BARM;
        LD_A(fA, 32768 + aq1);
        BARM; LGKM0; MM(fA, fBb, 4, 2); BARM;
        LD_B(fBa, 32768 + bq0);
        LGKM0; MM(fA, fBa, 4, 0);
    }
#undef ST_A
#undef ST_B
#undef LD_A
#undef LD_B
#undef MM
#undef BARM
#undef LGKM0

    float* Cp = (float*)C;
    if (EPI == 3) Cp += (size_t)blockIdx.z * M * N;

    #pragma unroll
    for (int m = 0; m < 8; ++m) {
        #pragma unroll
        for (int n = 0; n < 4; ++n) {
            #pragma unroll
            for (int r = 0; r < 4; ++r) {
                int row = bm + wm * 128 + m * 16 + quad * 4 + r;
                int col = bn + wn * 64 + n * 16 + l16;
                float v = acc[m][n][r];
                if (EPI == 0) {
                    ((bf16*)C)[(size_t)row * N + col] = __float2bfloat16(v);
                } else if (EPI == 1) {
                    float xx = v + bias[col];
                    float g = 0.5f * xx * (1.0f + erff(xx * 0.7071067811865475f));
                    ((bf16*)C)[(size_t)row * N + col] = __float2bfloat16(g);
                } else if (EPI == 2) {
                    ((float*)C)[(size_t)row * N + col] =
                        v + bias[col] + resid[(size_t)row * N + col];
                } else {
                    Cp[(size_t)row * N + col] = v;
                }
            }
        }
    }
}

// ---------------- RoPE (reference indexes sin/cos by BATCH, not position) --------
__global__ void rope_kernel(const bf16* __restrict__ in, bf16* __restrict__ out,
                            const float* __restrict__ sn, const float* __restrict__ cs,
                            int S, int D, int instride) {
    int row = blockIdx.x;
    int pos = row / S;                 // batch index — matches reference broadcast
    const int half = D >> 1;
    const bf16* r = in + (size_t)row * instride;
    bf16* o = out + (size_t)row * D;
    for (int j = threadIdx.x; j < half; j += 256) {
        uint32_t pr = *(const uint32_t*)(r + 2 * j);
        float x1 = __uint_as_float(pr << 16);
        float x2 = __uint_as_float(pr & 0xffff0000u);
        float c = cs[(size_t)pos * half + j], s = sn[(size_t)pos * half + j];
        o[j]        = __float2bfloat16(x1 * c - x2 * s);
        o[half + j] = __float2bfloat16(x1 * s + x2 * c);
    }
}

// ---------------- V transpose per head: v[b,s,h,d] (strided) -> vt[bh, d, s] -----
__global__ void vtrans_kernel(const bf16* __restrict__ v, bf16* __restrict__ vt,
                              int S, int D, int H, int instride) {
    __shared__ bf16 t[32][33];
    int bh = blockIdx.z, b = bh >> 4, h = bh & 15;
    int s0 = blockIdx.x * 32, d0 = blockIdx.y * 32;
    int tx = threadIdx.x & 31, ty = threadIdx.x >> 5;
    #pragma unroll
    for (int r = ty; r < 32; r += 8)
        t[r][tx] = v[(size_t)(b * S + s0 + r) * instride + h * 128 + d0 + tx];
    __syncthreads();
    #pragma unroll
    for (int r = ty; r < 32; r += 8)
        vt[((size_t)bh * 128 + d0 + r) * S + s0 + tx] = t[tx][r];
}

// ---------------- Flash attention, transposed-score form ----------------
__global__ __launch_bounds__(256, 4) void attn_kernel(
    const bf16* __restrict__ q, const bf16* __restrict__ k, const bf16* __restrict__ vt,
    float* __restrict__ o, int S, int D, int H)
{
    __shared__ __align__(16) char smem[40960];
    bf16* Ks = (bf16*)smem;                 // [64 k][128 d], 16B-block XOR swizzle
    bf16* Vs = (bf16*)(smem + 16384);       // [128 d][64 k], swizzled
    bf16* Ps = (bf16*)(smem + 32768);       // per-wave [16 q][64 k], swizzled

    const int tid = threadIdx.x, wid = tid >> 6, lane = tid & 63;
    const int quad = lane >> 4, l16 = lane & 15;
    const int bh = blockIdx.x, b = bh >> 4, h = bh & 15;
    const int qt = gridDim.y - 1 - blockIdx.y;     // big tiles dispatched first
    const float scale = 0.08838834764831845f;      // 1/sqrt(128)

    s16x8 qf[4];
    const bf16* qrow = q + ((size_t)(b * S + qt * 64 + wid * 16 + l16)) * D + h * 128;
    #pragma unroll
    for (int ks = 0; ks < 4; ++ks)
        qf[ks] = *(const s16x8*)(qrow + ks * 32 + quad * 8);

    f32x4 oacc[8] = {};
    float mstate = -INFINITY, lstate = 0.f;

    const bf16* kb0 = k + (size_t)(b * S) * D + h * 128;
    const bf16* vb0 = vt + (size_t)bh * 128 * S;
    bf16* psw = Ps + wid * 16 * 64;
    const int sw = l16 & 7;
    const int nch = qt + 1;

    for (int kc = 0; kc < nch; ++kc) {
        __syncthreads();
        #pragma unroll
        for (int c = 0; c < 4; ++c) {
            int choff = (wid * 4 + c) << 10;
            int off = choff + lane * 16;
            int rk = off >> 8, bk = (off & 255) >> 4;
            gload_lds16(kb0 + (size_t)(kc * 64 + rk) * D + ((bk ^ (rk & 7)) << 3),
                        (char*)Ks + choff);
            int rv = off >> 7, bv = (off & 127) >> 4;
            gload_lds16(vb0 + (size_t)rv * S + kc * 64 + ((bv ^ (rv & 7)) << 3),
                        (char*)Vs + choff);
        }
        __syncthreads();

        f32x4 sacc[4] = {};
        #pragma unroll
        for (int mt = 0; mt < 4; ++mt) {
            #pragma unroll
            for (int ks = 0; ks < 4; ++ks) {
                s16x8 kf = *(const s16x8*)(Ks + (mt * 16 + l16) * 128 +
                                           (((ks * 4 + quad) ^ sw) << 3));
                sacc[mt] = MFMA16(kf, qf[ks], sacc[mt]);
            }
        }

        const bool need_mask = (kc == qt);
        #pragma unroll
        for (int mt = 0; mt < 4; ++mt)
            #pragma unroll
            for (int r = 0; r < 4; ++r) {
                float vv = sacc[mt][r] * scale;
                if (need_mask) {
                    int kl = mt * 16 + quad * 4 + r;
                    if (kl > wid * 16 + l16) vv = -INFINITY;
                }
                sacc[mt][r] = vv;
            }

        float mx = fmaxf(fmaxf(fmaxf(sacc[0][0], sacc[0][1]), fmaxf(sacc[0][2], sacc[0][3])),
                         fmaxf(fmaxf(sacc[1][0], sacc[1][1]), fmaxf(sacc[1][2], sacc[1][3])));
        mx = fmaxf(mx, fmaxf(fmaxf(fmaxf(sacc[2][0], sacc[2][1]), fmaxf(sacc[2][2], sacc[2][3])),
                             fmaxf(fmaxf(sacc[3][0], sacc[3][1]), fmaxf(sacc[3][2], sacc[3][3]))));
        mx = fmaxf(mx, __shfl_xor(mx, 16, 64));
        mx = fmaxf(mx, __shfl_xor(mx, 32, 64));
        float mnew = fmaxf(mstate, mx);
        float alpha = __expf(mstate - mnew);
        float rs = 0.f;
        #pragma unroll
        for (int mt = 0; mt < 4; ++mt)
            #pragma unroll
            for (int r = 0; r < 4; ++r) {
                float p = __expf(sacc[mt][r] - mnew);
                sacc[mt][r] = p;
                rs += p;
            }
        rs += __shfl_xor(rs, 16, 64);
        rs += __shfl_xor(rs, 32, 64);
        lstate = lstate * alpha + rs;
        mstate = mnew;
        #pragma unroll
        for (int mt = 0; mt < 8; ++mt)
            #pragma unroll
            for (int r = 0; r < 4; ++r) oacc[mt][r] *= alpha;

        #pragma unroll
        for (int mt = 0; mt < 4; ++mt)
            #pragma unroll
            for (int r = 0; r < 4; ++r) {
                int kl = mt * 16 + quad * 4 + r;
                psw[l16 * 64 + (((kl >> 3) ^ sw) << 3) + (kl & 7)] =
                    __float2bfloat16(sacc[mt][r]);
            }

        #pragma unroll
        for (int ks2 = 0; ks2 < 2; ++ks2) {
            s16x8 pf = *(const s16x8*)(psw + l16 * 64 + (((ks2 * 4 + quad) ^ sw) << 3));
            #pragma unroll
            for (int mt = 0; mt < 8; ++mt) {
                s16x8 vf = *(const s16x8*)(Vs + (mt * 16 + l16) * 64 +
                                           (((ks2 * 4 + quad) ^ sw) << 3));
                oacc[mt] = MFMA16(vf, pf, oacc[mt]);
            }
        }
    }

    float inv = 1.0f / lstate;
    __syncthreads();
    float* osw = (float*)smem + wid * 16 * 130;
    #pragma unroll
    for (int mt = 0; mt < 8; ++mt)
        #pragma unroll
        for (int r = 0; r < 4; ++r)
            osw[l16 * 130 + mt * 16 + quad * 4 + r] = oacc[mt][r] * inv;
    float* obase = o + (size_t)(b * S + qt * 64 + wid * 16) * D + h * 128;
    #pragma unroll
    for (int r16 = 0; r16 < 16; ++r16) {
        float2 val = *(const float2*)(osw + r16 * 130 + lane * 2);
        *(float2*)(obase + (size_t)r16 * D + lane * 2) = val;
    }
}

// ---------------- LayerNorm over D=2048: x = a (+b) (+c) (+bias), dual out ------
__global__ __launch_bounds__(256) void ln_kernel(
    const float* __restrict__ a, const float* __restrict__ b,
    const float* __restrict__ c, const float* __restrict__ bias,
    float* __restrict__ outf, bf16* __restrict__ outb, int D)
{
    int row = blockIdx.x;
    const float* pa = a + (size_t)row * D;
    const float* pb = b ? b + (size_t)row * D : nullptr;
    const float* pc = c ? c + (size_t)row * D : nullptr;
    float v[8];
    float sum = 0.f, sq = 0.f;
    #pragma unroll
    for (int u = 0; u < 8; ++u) {
        int j = threadIdx.x + u * 256;
        float x = pa[j];
        if (pb) x += pb[j];
        if (pc) x += pc[j];
        if (bias) x += bias[j];
        v[u] = x; sum += x; sq += x * x;
    }
    #pragma unroll
    for (int off = 32; off > 0; off >>= 1) {
        sum += __shfl_down(sum, off, 64);
        sq  += __shfl_down(sq,  off, 64);
    }
    __shared__ float red[8];
    int wid = threadIdx.x >> 6, lane = threadIdx.x & 63;
    if (lane == 0) { red[wid] = sum; red[4 + wid] = sq; }
    __syncthreads();
    sum = red[0] + red[1] + red[2] + red[3];
    sq  = red[4] + red[5] + red[6] + red[7];
    float mean = sum / D;
    float var = sq / D - mean * mean;
    float rstd = rsqrtf(fmaxf(var, 0.f) + 1e-5f);
    float* pof = outf ? outf + (size_t)row * D : nullptr;
    bf16* pob = outb ? outb + (size_t)row * D : nullptr;
    #pragma unroll
    for (int u = 0; u < 8; ++u) {
        int j = threadIdx.x + u * 256;
        float y = (v[u] - mean) * rstd;
        if (pof) pof[j] = y;
        if (pob) pob[j] = __float2bfloat16(y);
    }
}

// ---------------- launch ----------------
// Workspace plan (proven budget: 232 MB).
//   [  0, 16) xb        -> qr (after QKV)   -> outb (after attn)
//   [ 16, 48) Wq^T/Wk^T -> kr@16-32         -> W1t (after LN1) -> W2t (after FFN1)
//   [ 32, 40) Wv^T      (dead after QKV)
//   [ 40, 88) qkv       -> attn fp32 @40-72 (after rope/vtrans)
//   [ 72,104) (qkv tail + vt@88-104) -> outf fp32 (after attn)
//   [104,168) h (FFN1 out, bf16 [M][8192])
//   [168,232) p0|p1 (FFN2 split-K fp32 partials)
extern "C" void kernel_launch(void* const* d_in, const int* in_sizes, int n_in,
                              void* d_out, int out_size, void* d_ws, size_t ws_size,
                              hipStream_t stream) {
    const float* x  = (const float*)d_in[0];
    const float* Wq = (const float*)d_in[1];
    const float* Wk = (const float*)d_in[2];
    const float* Wv = (const float*)d_in[3];
    const float* W1 = (const float*)d_in[4];
    const float* b1 = (const float*)d_in[5];
    const float* W2 = (const float*)d_in[6];
    const float* b2 = (const float*)d_in[7];
    const float* sn = (const float*)d_in[8];
    const float* cs = (const float*)d_in[9];

    const int B = 2, S = 2048, D = 2048, H = 16, Dff = 8192;
    const int M = B * S;                       // 4096
    const int NQKV = 3 * D;                    // 6144
    char* ws = (char*)d_ws;
    const size_t MB = 1024 * 1024;

    const size_t o_xb   = 0;                   // bf16 [M][D], 16 MB
    const size_t o_Wqkv = 16 * MB;             // bf16 [6144][2048], 24 MB
    const size_t o_qkv  = 40 * MB;             // bf16 [M][6144], 48 MB
    const size_t o_qr   = 0;                   // bf16 16 MB (xb dead)
    const size_t o_kr   = 16 * MB;             // bf16 16 MB (Wq^T/Wk^T dead)
    const size_t o_vt   = 88 * MB;             // bf16 [BH][128][S], 16 MB
    const size_t o_attn = 40 * MB;             // fp32 [M][D], 32 MB (qkv dead)
    const size_t o_outb = 0;                   // bf16 16 MB (qr dead)
    const size_t o_outf = 72 * MB;             // fp32 32 MB (qkv tail + vt dead)
    const size_t o_W1t  = 16 * MB;             // bf16 [8192][2048], 32 MB (kr/attn dead)
    const size_t o_h    = 104 * MB;            // bf16 [M][8192], 64 MB
    const size_t o_W2t  = 16 * MB;             // bf16 [2048][8192], 32 MB (W1t dead)
    const size_t o_p    = 168 * MB;            // fp32 2x[M][D], 64 MB

    // 1. x -> bf16; Wq/Wk/Wv -> stacked transposed bf16 [6144][2048]
    long nx = (long)M * D;
    cvt_f32_bf16<<<nx / 2048, 256, 0, stream>>>(x, (bf16*)(ws + o_xb), nx);
    transpose_cvt<<<dim3(D / 32, D / 32), 256, 0, stream>>>(
        Wq, (bf16*)(ws + o_Wqkv), D, D);
    transpose_cvt<<<dim3(D / 32, D / 32), 256, 0, stream>>>(
        Wk, (bf16*)(ws + o_Wqkv) + (size_t)D * D, D, D);
    transpose_cvt<<<dim3(D / 32, D / 32), 256, 0, stream>>>(
        Wv, (bf16*)(ws + o_Wqkv) + 2 * (size_t)D * D, D, D);

    // 2. fused QKV projection: [M][2048] x [6144][2048]^T -> [M][6144]
    gemm_pipe<0, 1><<<dim3(M / 256, NQKV / 256), 512, 0, stream>>>(
        (bf16*)(ws + o_xb), (bf16*)(ws + o_Wqkv), ws + o_qkv, nullptr, nullptr,
        M, NQKV, D);

    // 3. RoPE + V transpose (strided reads from fused buffer)
    rope_kernel<<<M, 256, 0, stream>>>((bf16*)(ws + o_qkv), (bf16*)(ws + o_qr),
                                       sn, cs, S, D, NQKV);
    rope_kernel<<<M, 256, 0, stream>>>((bf16*)(ws + o_qkv) + D, (bf16*)(ws + o_kr),
                                       sn, cs, S, D, NQKV);
    vtrans_kernel<<<dim3(S / 32, 4, B * H), 256, 0, stream>>>(
        (bf16*)(ws + o_qkv) + 2 * D, (bf16*)(ws + o_vt), S, D, H, NQKV);

    // 4. causal flash attention -> fp32 [M][D]
    attn_kernel<<<dim3(B * H, S / 64), 256, 0, stream>>>(
        (bf16*)(ws + o_qr), (bf16*)(ws + o_kr), (bf16*)(ws + o_vt),
        (float*)(ws + o_attn), S, D, H);

    // 5. LN(attn + x) -> outf (fp32, residual for LN2) + outb (bf16, FFN1 input)
    ln_kernel<<<M, 256, 0, stream>>>((float*)(ws + o_attn), x, nullptr, nullptr,
                                     (float*)(ws + o_outf), (bf16*)(ws + o_outb), D);

    // 6. W1^T (late: reuses kr/attn regions), then FFN1: gelu(out@W1+b1) -> bf16 h
    transpose_cvt<<<dim3(Dff / 32, D / 32), 256, 0, stream>>>(
        W1, (bf16*)(ws + o_W1t), D, Dff);
    gemm_pipe<1, 1><<<dim3(M / 256, Dff / 256), 512, 0, stream>>>(
        (bf16*)(ws + o_outb), (bf16*)(ws + o_W1t), ws + o_h, b1, nullptr, M, Dff, D);

    // 7. W2^T (late: reuses W1t region), then FFN2 split-K=2 -> p0|p1 fp32
    transpose_cvt<<<dim3(D / 32, Dff / 32), 256, 0, stream>>>(
        W2, (bf16*)(ws + o_W2t), Dff, D);
    gemm_pipe<3, 2><<<dim3(M / 256, D / 256, 2), 512, 0, stream>>>(
        (bf16*)(ws + o_h), (bf16*)(ws + o_W2t), ws + o_p, nullptr, nullptr, M, D, Dff);

    // 8. LN2( p0 + p1 + outf + b2 ) -> d_out fp32
    ln_kernel<<<M, 256, 0, stream>>>((float*)(ws + o_p),
                                     (float*)(ws + o_p) + (size_t)M * D,
                                     (float*)(ws + o_outf), b2,
                                     (float*)d_out, nullptr, D);
}